// Round 5
// baseline (152.261 us; speedup 1.0000x reference)
//
#include <hip/hip_runtime.h>
#include <math.h>

#define B_    8
#define Q_    900
#define NCLS_ 11
#define NANC_ 100
#define H_    200
#define W_    200
#define C_    256
#define QTR_  (W_ / 4)      // 50 pixels owned per wave (contiguous)

// ---------------------------------------------------------------------------
// Kernel 1: scores + rank-based top-k + box->pixel coords (one block per batch)
// (unchanged — proven in rounds 1-4)
// ---------------------------------------------------------------------------
__global__ __launch_bounds__(1024) void segdet_topk_kernel(
    const float* __restrict__ pred_boxes,   // [B,Q,4]
    const float* __restrict__ pred_logits,  // [B,Q,NCLS]
    const float* __restrict__ view,         // [B,5,5]
    int*  __restrict__ ws_idx,              // [B,NANC]  selected q index
    int4* __restrict__ ws_box)              // [B,NANC]  (x0,y0,x1,y1) clipped ints
{
    const int b = blockIdx.x;
    const int q = threadIdx.x;

    __shared__ float sc[Q_];

    if (q < Q_) {
        const float* l = pred_logits + (b * Q_ + q) * NCLS_;
        float v[NCLS_];
        float m = -INFINITY;
        #pragma unroll
        for (int i = 0; i < NCLS_; ++i) { v[i] = l[i]; m = fmaxf(m, v[i]); }
        float s = 0.0f, e10 = -INFINITY;
        #pragma unroll
        for (int i = 0; i < NCLS_; ++i) {
            float e = expf(v[i] - m);
            s += e;
            if (i < NCLS_ - 1) e10 = fmaxf(e10, e);   // exclude background (last)
        }
        sc[q] = e10 / s;
    }
    __syncthreads();

    if (q < Q_) {
        const float my = sc[q];
        int rank = 0;
        for (int j = 0; j < Q_; ++j) {
            float o = sc[j];
            rank += (o > my) || (o == my && j < q);   // top_k tie-break: lower idx first
        }
        if (rank < NANC_) {
            // box -> xyxy -> view transform -> trunc int -> clip, in double so the
            // int-truncation boundary matches the reference exactly.
            const float* bx = pred_boxes + (b * Q_ + q) * 4;
            double cx = (double)bx[0], cy = (double)bx[1];
            double w  = exp((double)bx[2]);
            double h  = exp((double)bx[3]);
            double p[5] = { cx - 0.5 * w, cy - 0.5 * h,
                            cx + 0.5 * w, cy + 0.5 * h, 1.0 };
            const float* v5 = view + b * 25;
            int ico[4];
            #pragma unroll
            for (int i = 0; i < 4; ++i) {
                double acc = 0.0;
                #pragma unroll
                for (int j = 0; j < 5; ++j) acc += (double)v5[i * 5 + j] * p[j];
                ico[i] = (int)acc;                    // trunc toward zero == astype(int32)
            }
            int x0 = min(max(ico[0], 0), W_);
            int y0 = min(max(ico[1], 0), H_);
            int x1 = min(max(ico[2], 0), W_);
            int y1 = min(max(ico[3], 0), H_);
            const int slot = b * NANC_ + rank;        // rank unique -> no atomics
            ws_idx[slot] = q;
            ws_box[slot] = make_int4(x0, y0, x1, y1);
        }
    }
}

// ---------------------------------------------------------------------------
// Kernel 2: BEV splat, contiguous-quarter + pipelined segment walk.
// One block per (b,h) row, 4 waves; wave wv owns pixels [50wv, 50wv+50).
// Lane owns 4 channels (float4 => 1KB/wave-store). Per wave: batch-load init
// coverage at its start pixel (independent loads), then walk only its own
// quarter's CSR entries; each entry's feature load is issued BEFORE the
// segment's store run so the ~250cy L2 latency hides under the store stream.
// Entry word for the next segment is prefetched one iteration ahead.
// Shuffle-based scan (2 barriers) replaces the 16-barrier block scan.
// No runtime-indexed private arrays (scratch-free).
// ---------------------------------------------------------------------------
__global__ __launch_bounds__(256) void segdet_bev_kernel(
    const float* __restrict__ box_feats,    // [B,Q,C]
    const int*   __restrict__ ws_idx,       // [B,NANC]
    const int4*  __restrict__ ws_box,       // [B,NANC]
    float* __restrict__ bev,                // [B,H,W,C]
    float* __restrict__ mask)               // [B,H,W] (0/1 floats)
{
    const int b   = blockIdx.x / H_;
    const int h   = blockIdx.x % H_;
    const int tid = threadIdx.x;
    const int ln  = tid & 63;
    const int wv  = tid >> 6;

    __shared__ int s_box[NANC_];            // x0 | x1<<8 | q<<16 (packed)
    __shared__ int s_nact;
    __shared__ int s_nopen[W_];             // # opens at pixel w
    __shared__ int s_ofs[W_];               // CSR offsets (exclusive scan)
    __shared__ int s_ent[2 * NANC_];        // pix | q<<8 | (close ? 1<<31 : 0)
    __shared__ int s_wsum[4];

    // ---- wave-0 ballot compaction of row-active anchors (deterministic order)
    if (tid < 64) {
        int na = 0;
        #pragma unroll
        for (int it = 0; it < 2; ++it) {
            int k = it * 64 + ln;
            bool act = false;
            int packed = 0;
            if (k < NANC_) {
                int4 bx = ws_box[b * NANC_ + k];
                int qi  = ws_idx[b * NANC_ + k];
                act = (bx.y <= h) && (h < bx.w) && (bx.x < bx.z);
                packed = bx.x | (bx.z << 8) | (qi << 16);
            }
            unsigned long long ball = __ballot(act);
            int pos = na + (int)__popcll(ball & ((1ull << ln) - 1ull));
            if (act) s_box[pos] = packed;
            na += (int)__popcll(ball);
        }
        if (ln == 0) s_nact = na;
    }
    __syncthreads();

    const int nact = s_nact;

    // ---- per-pixel open/close counts + coverage (mask), in parallel
    int ntot = 0;
    if (tid < W_) {
        int nopen = 0, nclose = 0, cov = 0;
        for (int k = 0; k < nact; ++k) {
            int pk = s_box[k];                 // uniform LDS broadcast
            int x0 = pk & 0xFF, x1 = (pk >> 8) & 0xFF;
            nopen  += (x0 == tid);
            nclose += (x1 == tid);             // x1==200 auto-excluded (tid<200)
            cov    += (x0 <= tid) && (tid < x1);
        }
        s_nopen[tid] = nopen;
        ntot = nopen + nclose;
        mask[(size_t)(b * H_ + h) * W_ + tid] = (cov > 0) ? 1.0f : 0.0f;
    }

    // ---- shuffle-based inclusive scan (6 steps) + cross-wave combine
    int incl = ntot;
    #pragma unroll
    for (int d = 1; d < 64; d <<= 1) {
        int u = __shfl_up(incl, d);
        incl = (ln >= d) ? incl + u : incl;
    }
    if (ln == 63) s_wsum[wv] = incl;
    __syncthreads();
    int prev = 0;
    #pragma unroll
    for (int j = 0; j < 4; ++j) prev += (j < wv) ? s_wsum[j] : 0;
    const int ne = s_wsum[0] + s_wsum[1] + s_wsum[2] + s_wsum[3];
    if (tid < W_) s_ofs[tid] = prev + incl - ntot;   // exclusive scan
    __syncthreads();

    // ---- CSR entry scatter: one thread per active box, stable k-order
    if (tid < nact) {
        int pk = s_box[tid];
        int x0 = pk & 0xFF, x1 = (pk >> 8) & 0xFF, q = pk >> 16;
        int ro = 0, rc = 0;
        for (int j = 0; j < tid; ++j) {
            int pj = s_box[j];
            ro += ((pj & 0xFF) == x0);
            rc += (((pj >> 8) & 0xFF) == x1);
        }
        s_ent[s_ofs[x0] + ro] = x0 | (q << 8);                            // open
        if (x1 < W_)
            s_ent[s_ofs[x1] + s_nopen[x1] + rc] = x1 | (q << 8) | (1 << 31); // close
    }
    __syncthreads();

    // ---- per-wave contiguous quarter [start, end)
    const int start = wv * QTR_;
    const int end   = start + QTR_;

    const float* fbase = box_feats + (size_t)b * Q_ * C_ + ln * 4;
    float* obase = bev + (size_t)(b * H_ + h) * W_ * C_ + ln * 4;

    // init: coverage state at pixel `start` (k-order; wave-uniform branch,
    // loads independent -> single L2 latency for the whole batch)
    float4 acc = make_float4(0.f, 0.f, 0.f, 0.f);
    int cnt = 0;
    for (int k = 0; k < nact; ++k) {
        int pk = s_box[k];
        int x0 = pk & 0xFF, x1 = (pk >> 8) & 0xFF;
        if (x0 <= start && start < x1) {
            const float4 f = *(const float4*)(fbase + (size_t)(pk >> 16) * C_);
            acc.x += f.x; acc.y += f.y; acc.z += f.z; acc.w += f.w;
            ++cnt;
        }
    }

    // entries strictly inside (start, end): [s_ofs[start+1], s_ofs[end])
    int e    = s_ofs[start + 1];
    int eend = (end < W_) ? s_ofs[end] : ne;
    int w    = start;
    int entc = (e < eend) ? s_ent[e] : 0;
    while (e < eend) {
        int entn = (e + 1 < eend) ? s_ent[e + 1] : 0;   // prefetch next entry word
        const int epix = entc & 0xFF;
        const float4 f = *(const float4*)(fbase +
                           (size_t)((entc >> 8) & 0x3FF) * C_);  // issued pre-stores
        if (cnt == 0) acc = make_float4(0.f, 0.f, 0.f, 0.f);     // exact zeros
        for (; w < epix; ++w)
            *(float4*)(obase + (size_t)w * C_) = acc;            // 1KB/wave stores
        if (entc < 0) { acc.x -= f.x; acc.y -= f.y; acc.z -= f.z; acc.w -= f.w; --cnt; }
        else          { acc.x += f.x; acc.y += f.y; acc.z += f.z; acc.w += f.w; ++cnt; }
        entc = entn;
        ++e;
    }
    if (cnt == 0) acc = make_float4(0.f, 0.f, 0.f, 0.f);
    for (; w < end; ++w)
        *(float4*)(obase + (size_t)w * C_) = acc;
}

// ---------------------------------------------------------------------------
extern "C" void kernel_launch(void* const* d_in, const int* in_sizes, int n_in,
                              void* d_out, int out_size, void* d_ws, size_t ws_size,
                              hipStream_t stream) {
    const float* pred_boxes  = (const float*)d_in[0];
    const float* pred_logits = (const float*)d_in[1];
    const float* box_feats   = (const float*)d_in[2];
    const float* view        = (const float*)d_in[3];

    float* bev  = (float*)d_out;
    float* mask = bev + (size_t)B_ * H_ * W_ * C_;

    int*  ws_idx = (int*)d_ws;                            // 800 ints = 3200 B
    int4* ws_box = (int4*)((char*)d_ws + 3200);           // 800 int4 (16B aligned)

    segdet_topk_kernel<<<B_, 1024, 0, stream>>>(pred_boxes, pred_logits, view,
                                                ws_idx, ws_box);
    segdet_bev_kernel<<<B_ * H_, 256, 0, stream>>>(box_feats, ws_idx, ws_box,
                                                   bev, mask);
}

// Round 6
// 138.506 us; speedup vs baseline: 1.0993x; 1.0993x over previous
//
#include <hip/hip_runtime.h>
#include <math.h>

#define B_    8
#define Q_    900
#define NCLS_ 11
#define NANC_ 100
#define H_    200
#define W_    200
#define C_    256
#define NEPAD_ 208          // 2*NANC_ rounded up to multiple of 8 (batch size)

// ---------------------------------------------------------------------------
// Kernel 1: scores + rank-based top-k + box->pixel coords (one block per batch)
// (unchanged — proven rounds 1-5)
// ---------------------------------------------------------------------------
__global__ __launch_bounds__(1024) void segdet_topk_kernel(
    const float* __restrict__ pred_boxes,   // [B,Q,4]
    const float* __restrict__ pred_logits,  // [B,Q,NCLS]
    const float* __restrict__ view,         // [B,5,5]
    int*  __restrict__ ws_idx,              // [B,NANC]  selected q index
    int4* __restrict__ ws_box)              // [B,NANC]  (x0,y0,x1,y1) clipped ints
{
    const int b = blockIdx.x;
    const int q = threadIdx.x;

    __shared__ float sc[Q_];

    if (q < Q_) {
        const float* l = pred_logits + (b * Q_ + q) * NCLS_;
        float v[NCLS_];
        float m = -INFINITY;
        #pragma unroll
        for (int i = 0; i < NCLS_; ++i) { v[i] = l[i]; m = fmaxf(m, v[i]); }
        float s = 0.0f, e10 = -INFINITY;
        #pragma unroll
        for (int i = 0; i < NCLS_; ++i) {
            float e = expf(v[i] - m);
            s += e;
            if (i < NCLS_ - 1) e10 = fmaxf(e10, e);   // exclude background (last)
        }
        sc[q] = e10 / s;
    }
    __syncthreads();

    if (q < Q_) {
        const float my = sc[q];
        int rank = 0;
        for (int j = 0; j < Q_; ++j) {
            float o = sc[j];
            rank += (o > my) || (o == my && j < q);   // top_k tie-break: lower idx first
        }
        if (rank < NANC_) {
            // box -> xyxy -> view transform -> trunc int -> clip, in double so the
            // int-truncation boundary matches the reference exactly.
            const float* bx = pred_boxes + (b * Q_ + q) * 4;
            double cx = (double)bx[0], cy = (double)bx[1];
            double w  = exp((double)bx[2]);
            double h  = exp((double)bx[3]);
            double p[5] = { cx - 0.5 * w, cy - 0.5 * h,
                            cx + 0.5 * w, cy + 0.5 * h, 1.0 };
            const float* v5 = view + b * 25;
            int ico[4];
            #pragma unroll
            for (int i = 0; i < 4; ++i) {
                double acc = 0.0;
                #pragma unroll
                for (int j = 0; j < 5; ++j) acc += (double)v5[i * 5 + j] * p[j];
                ico[i] = (int)acc;                    // trunc toward zero == astype(int32)
            }
            int x0 = min(max(ico[0], 0), W_);
            int y0 = min(max(ico[1], 0), H_);
            int x1 = min(max(ico[2], 0), W_);
            int y1 = min(max(ico[3], 0), H_);
            const int slot = b * NANC_ + rank;        // rank unique -> no atomics
            ws_idx[slot] = q;
            ws_box[slot] = make_int4(x0, y0, x1, y1);
        }
    }
}

// ---------------------------------------------------------------------------
// Kernel 2: BEV splat — round-4 balanced interleave + batched-8 entry pipeline.
// One block per (b,h) row, 4 waves; wave wv owns pixels {wv, wv+4, ...} so
// per-wave work is identical (no imbalance). All waves walk the full entry
// list; entries processed in batches of 8: two ds_read_b128 fetch 8 packed
// entry words (uniform broadcast), then all 8 feature float4 loads are issued
// BEFORE the batch's store-runs (8 independent L2 loads in flight), then 8
// static {store-run, apply} steps. Sentinel padding (pix=0xFF) keeps control
// flow uniform. Named registers only — scratch-free.
// ---------------------------------------------------------------------------
__global__ __launch_bounds__(256) void segdet_bev_kernel(
    const float* __restrict__ box_feats,    // [B,Q,C]
    const int*   __restrict__ ws_idx,       // [B,NANC]
    const int4*  __restrict__ ws_box,       // [B,NANC]
    float* __restrict__ bev,                // [B,H,W,C]
    float* __restrict__ mask)               // [B,H,W] (0/1 floats)
{
    const int b   = blockIdx.x / H_;
    const int h   = blockIdx.x % H_;
    const int tid = threadIdx.x;
    const int ln  = tid & 63;
    const int wv  = tid >> 6;

    __shared__ int s_box[NANC_];            // x0 | x1<<8 | q<<16 (packed)
    __shared__ int s_nact;
    __shared__ int s_nopen[W_];             // # opens at pixel w
    __shared__ int s_ofs[W_];               // CSR offsets (exclusive scan)
    __shared__ __align__(16) int s_ent[NEPAD_];  // pix | q<<8 | (close ? 1<<31 : 0)
    __shared__ int s_wsum[4];

    // ---- wave-0 ballot compaction of row-active anchors (deterministic order)
    if (tid < 64) {
        int na = 0;
        #pragma unroll
        for (int it = 0; it < 2; ++it) {
            int k = it * 64 + ln;
            bool act = false;
            int packed = 0;
            if (k < NANC_) {
                int4 bx = ws_box[b * NANC_ + k];
                int qi  = ws_idx[b * NANC_ + k];
                act = (bx.y <= h) && (h < bx.w) && (bx.x < bx.z);
                packed = bx.x | (bx.z << 8) | (qi << 16);
            }
            unsigned long long ball = __ballot(act);
            int pos = na + (int)__popcll(ball & ((1ull << ln) - 1ull));
            if (act) s_box[pos] = packed;
            na += (int)__popcll(ball);
        }
        if (ln == 0) s_nact = na;
    }
    __syncthreads();

    const int nact = s_nact;

    // ---- per-pixel open/close counts + coverage (mask); sentinel-init s_ent
    int ntot = 0;
    if (tid < W_) {
        int nopen = 0, nclose = 0, cov = 0;
        for (int k = 0; k < nact; ++k) {
            int pk = s_box[k];                 // uniform LDS broadcast
            int x0 = pk & 0xFF, x1 = (pk >> 8) & 0xFF;
            nopen  += (x0 == tid);
            nclose += (x1 == tid);             // x1==200 auto-excluded (tid<200)
            cov    += (x0 <= tid) && (tid < x1);
        }
        s_nopen[tid] = nopen;
        ntot = nopen + nclose;
        mask[(size_t)(b * H_ + h) * W_ + tid] = (cov > 0) ? 1.0f : 0.0f;
    }
    if (tid < NEPAD_) s_ent[tid] = 0xFF;       // sentinel: pix=255, q=0, sign +

    // ---- shuffle-based inclusive scan (6 steps) + cross-wave combine
    int incl = ntot;
    #pragma unroll
    for (int d = 1; d < 64; d <<= 1) {
        int u = __shfl_up(incl, d);
        incl = (ln >= d) ? incl + u : incl;
    }
    if (ln == 63) s_wsum[wv] = incl;
    __syncthreads();                            // also covers sentinel init
    int prev = 0;
    #pragma unroll
    for (int j = 0; j < 4; ++j) prev += (j < wv) ? s_wsum[j] : 0;
    const int ne = s_wsum[0] + s_wsum[1] + s_wsum[2] + s_wsum[3];
    if (tid < W_) s_ofs[tid] = prev + incl - ntot;   // exclusive scan
    __syncthreads();

    // ---- CSR entry scatter: one thread per active box, stable k-order
    if (tid < nact) {
        int pk = s_box[tid];
        int x0 = pk & 0xFF, x1 = (pk >> 8) & 0xFF, q = pk >> 16;
        int ro = 0, rc = 0;
        for (int j = 0; j < tid; ++j) {
            int pj = s_box[j];
            ro += ((pj & 0xFF) == x0);
            rc += (((pj >> 8) & 0xFF) == x1);
        }
        s_ent[s_ofs[x0] + ro] = x0 | (q << 8);                            // open
        if (x1 < W_)
            s_ent[s_ofs[x1] + s_nopen[x1] + rc] = x1 | (q << 8) | (1 << 31); // close
    }
    __syncthreads();

    // ---- main loop: batched-8 entry pipeline, interleaved pixel ownership
    const float* fbase = box_feats + (size_t)b * Q_ * C_ + ln * 4;
    float* obase = bev + (size_t)(b * H_ + h) * W_ * C_ + ln * 4;

    float4 acc = make_float4(0.f, 0.f, 0.f, 0.f);
    int cnt = 0;
    int w = wv;
    const int nb = (ne + 7) >> 3;               // uniform across all waves

#define STEP_(PK, F)                                                          \
    {                                                                         \
        const int pk_ = (PK);                                                 \
        const int px_ = pk_ & 0xFF;                                           \
        const int lim_ = (px_ < W_) ? px_ : W_;                               \
        for (; w < lim_; w += 4)                                              \
            *(float4*)(obase + (size_t)w * C_) = acc;                         \
        if (px_ < W_) {                                                       \
            if (pk_ < 0) { acc.x -= (F).x; acc.y -= (F).y;                    \
                           acc.z -= (F).z; acc.w -= (F).w; --cnt; }           \
            else         { acc.x += (F).x; acc.y += (F).y;                    \
                           acc.z += (F).z; acc.w += (F).w; ++cnt; }           \
            if (cnt == 0) acc = make_float4(0.f, 0.f, 0.f, 0.f);              \
        }                                                                     \
    }

    for (int bi = 0; bi < nb; ++bi) {
        const int4 ew0 = *(const int4*)&s_ent[bi * 8];        // broadcast b128
        const int4 ew1 = *(const int4*)&s_ent[bi * 8 + 4];
        // issue all 8 feature loads up front (independent, 8-deep in flight)
        const float4 f0 = *(const float4*)(fbase + (size_t)((ew0.x >> 8) & 0x3FF) * C_);
        const float4 f1 = *(const float4*)(fbase + (size_t)((ew0.y >> 8) & 0x3FF) * C_);
        const float4 f2 = *(const float4*)(fbase + (size_t)((ew0.z >> 8) & 0x3FF) * C_);
        const float4 f3 = *(const float4*)(fbase + (size_t)((ew0.w >> 8) & 0x3FF) * C_);
        const float4 f4 = *(const float4*)(fbase + (size_t)((ew1.x >> 8) & 0x3FF) * C_);
        const float4 f5 = *(const float4*)(fbase + (size_t)((ew1.y >> 8) & 0x3FF) * C_);
        const float4 f6 = *(const float4*)(fbase + (size_t)((ew1.z >> 8) & 0x3FF) * C_);
        const float4 f7 = *(const float4*)(fbase + (size_t)((ew1.w >> 8) & 0x3FF) * C_);
        STEP_(ew0.x, f0); STEP_(ew0.y, f1); STEP_(ew0.z, f2); STEP_(ew0.w, f3);
        STEP_(ew1.x, f4); STEP_(ew1.y, f5); STEP_(ew1.z, f6); STEP_(ew1.w, f7);
    }
#undef STEP_
    for (; w < W_; w += 4)
        *(float4*)(obase + (size_t)w * C_) = acc;
}

// ---------------------------------------------------------------------------
extern "C" void kernel_launch(void* const* d_in, const int* in_sizes, int n_in,
                              void* d_out, int out_size, void* d_ws, size_t ws_size,
                              hipStream_t stream) {
    const float* pred_boxes  = (const float*)d_in[0];
    const float* pred_logits = (const float*)d_in[1];
    const float* box_feats   = (const float*)d_in[2];
    const float* view        = (const float*)d_in[3];

    float* bev  = (float*)d_out;
    float* mask = bev + (size_t)B_ * H_ * W_ * C_;

    int*  ws_idx = (int*)d_ws;                            // 800 ints = 3200 B
    int4* ws_box = (int4*)((char*)d_ws + 3200);           // 800 int4 (16B aligned)

    segdet_topk_kernel<<<B_, 1024, 0, stream>>>(pred_boxes, pred_logits, view,
                                                ws_idx, ws_box);
    segdet_bev_kernel<<<B_ * H_, 256, 0, stream>>>(box_feats, ws_idx, ws_box,
                                                   bev, mask);
}